// Round 1
// baseline (449.460 us; speedup 1.0000x reference)
//
#include <hip/hip_runtime.h>
#include <cstdint>
#include <cstddef>

#define Bv 8
#define Av 16384
#define Sv 2048
#define Dv 512
#define OUTv 512
#define Mv (Bv * Sv)

using u16 = unsigned short;
using f32x4 = __attribute__((ext_vector_type(4))) float;
using bf16x8 = __attribute__((ext_vector_type(8))) short;

__device__ __forceinline__ u16 f2bf(float x) {
  union { float f; uint32_t u; } v; v.f = x;
  uint32_t u = v.u;
  uint32_t r = u + 0x7FFFu + ((u >> 16) & 1u);   // round-to-nearest-even
  return (u16)(r >> 16);
}
__device__ __forceinline__ float bf2f(u16 h) {
  union { uint32_t u; float f; } v; v.u = ((uint32_t)h) << 16; return v.f;
}

// ---------------------------------------------------------------------------
// Kernel 1: segment-mean pooling. Atoms are sorted by residue id per batch,
// so block (b,s) binary-searches its contiguous atom range — no atomics.
// 128 threads, 4 cols each (float4 coalesced row reads).
// ---------------------------------------------------------------------------
__global__ __launch_bounds__(128)
void pool_kernel(const float* __restrict__ rep, const int* __restrict__ res_ids,
                 const int* __restrict__ aa_len, u16* __restrict__ pooled,
                 int* __restrict__ counts) {
  const int bs = blockIdx.x;
  const int b = bs >> 11;          // /Sv
  const int s = bs & (Sv - 1);
  int alen = aa_len[b];
  alen = alen < 0 ? 0 : (alen > Av ? Av : alen);
  const int* ids = res_ids + b * Av;
  int lo = 0, hi = alen;
  while (lo < hi) { int mid = (lo + hi) >> 1; if (ids[mid] < s) lo = mid + 1; else hi = mid; }
  const int start = lo;
  hi = alen;
  while (lo < hi) { int mid = (lo + hi) >> 1; if (ids[mid] <= s) lo = mid + 1; else hi = mid; }
  const int end = lo;
  const int cnt = end - start;

  const int t = threadIdx.x;       // 0..127, cols 4t..4t+3
  float a0 = 0.f, a1 = 0.f, a2 = 0.f, a3 = 0.f;
  const float* base = rep + (size_t)b * Av * Dv + t * 4;
  for (int a = start; a < end; ++a) {
    float4 v = *(const float4*)(base + (size_t)a * Dv);
    a0 += v.x; a1 += v.y; a2 += v.z; a3 += v.w;
  }
  const float inv = cnt > 0 ? 1.0f / (float)cnt : 0.0f;
  ushort4 o = { f2bf(a0 * inv), f2bf(a1 * inv), f2bf(a2 * inv), f2bf(a3 * inv) };
  *(ushort4*)(pooled + (size_t)bs * Dv + t * 4) = o;
  if (t == 0) counts[bs] = cnt;
}

// ---------------------------------------------------------------------------
// Kernel 2: W (fp32) -> bf16
// ---------------------------------------------------------------------------
__global__ __launch_bounds__(256)
void wconv_kernel(const float* __restrict__ W, u16* __restrict__ Wb) {
  const int i = (blockIdx.x * 256 + threadIdx.x) * 4;
  float4 v = *(const float4*)(W + i);
  ushort4 o = { f2bf(v.x), f2bf(v.y), f2bf(v.z), f2bf(v.w) };
  *(ushort4*)(Wb + i) = o;
}

// ---------------------------------------------------------------------------
// Kernel 3: per-batch sum of filled pooled rows + filled count (atomics into
// zeroed workspace). grid (B, 16) x 128 threads; thread t handles cols 4t..4t+3.
// ---------------------------------------------------------------------------
__global__ __launch_bounds__(128)
void avg_kernel(const u16* __restrict__ pooled, const int* __restrict__ counts,
                const int* __restrict__ seq_len, float* __restrict__ avg_sum,
                int* __restrict__ n_fill) {
  const int b = blockIdx.x;
  const int chunk = blockIdx.y;    // 0..15
  const int t = threadIdx.x;       // 0..127
  int slen = seq_len[b];
  slen = slen < 0 ? 0 : (slen > Sv ? Sv : slen);
  const int s0 = chunk * 128;
  float a0 = 0.f, a1 = 0.f, a2 = 0.f, a3 = 0.f;
  int filled = 0;
  for (int s = s0; s < s0 + 128; ++s) {
    if (s < slen && counts[b * Sv + s] > 0) {
      ++filled;
      ushort4 v = *(const ushort4*)(pooled + ((size_t)(b * Sv + s)) * Dv + t * 4);
      a0 += bf2f(v.x); a1 += bf2f(v.y); a2 += bf2f(v.z); a3 += bf2f(v.w);
    }
  }
  atomicAdd(&avg_sum[b * Dv + t * 4 + 0], a0);
  atomicAdd(&avg_sum[b * Dv + t * 4 + 1], a1);
  atomicAdd(&avg_sum[b * Dv + t * 4 + 2], a2);
  atomicAdd(&avg_sum[b * Dv + t * 4 + 3], a3);
  if (t == 0) atomicAdd(&n_fill[b], filled);
}

// ---------------------------------------------------------------------------
// Kernel 4: rows with cnt==0 (in-range) get the per-batch filled average;
// rows out of seq range get zeros. Nearly all blocks exit immediately.
// ---------------------------------------------------------------------------
__global__ __launch_bounds__(64)
void fixup_kernel(u16* __restrict__ pooled, const int* __restrict__ counts,
                  const int* __restrict__ seq_len, const float* __restrict__ avg_sum,
                  const int* __restrict__ n_fill) {
  const int bs = blockIdx.x;
  const int b = bs >> 11;
  const int s = bs & (Sv - 1);
  int slen = seq_len[b];
  slen = slen < 0 ? 0 : (slen > Sv ? Sv : slen);
  const int cnt = counts[bs];
  const int t = threadIdx.x;       // 0..63, cols 8t..8t+7
  if (s >= slen) {
    if (cnt != 0) {
      ushort4 z = {0, 0, 0, 0};
      *(ushort4*)(pooled + (size_t)bs * Dv + t * 8) = z;
      *(ushort4*)(pooled + (size_t)bs * Dv + t * 8 + 4) = z;
    }
    return;
  }
  if (cnt > 0) return;
  const int nf = n_fill[b];
  const float inv = 1.0f / (float)(nf > 0 ? nf : 1);
  float4 v0 = *(const float4*)(avg_sum + b * Dv + t * 8);
  float4 v1 = *(const float4*)(avg_sum + b * Dv + t * 8 + 4);
  ushort4 o0 = { f2bf(v0.x * inv), f2bf(v0.y * inv), f2bf(v0.z * inv), f2bf(v0.w * inv) };
  ushort4 o1 = { f2bf(v1.x * inv), f2bf(v1.y * inv), f2bf(v1.z * inv), f2bf(v1.w * inv) };
  *(ushort4*)(pooled + (size_t)bs * Dv + t * 8) = o0;
  *(ushort4*)(pooled + (size_t)bs * Dv + t * 8 + 4) = o1;
}

// ---------------------------------------------------------------------------
// Kernel 5: out[m,n] = sum_k pooled[m,k] * W[n,k] + bias[n]   (bf16 MFMA)
// Block tile 128x128, 4 waves of 64x64 (4x4 of 16x16x32 MFMA), BK=32.
// LDS rows padded to 40 bf16 to break power-of-2 bank aliasing.
// ---------------------------------------------------------------------------
#define BM 128
#define BN 128
#define BK 32
#define LDT 40

__global__ __launch_bounds__(256, 2)
void gemm_kernel(const u16* __restrict__ A, const u16* __restrict__ Bw,
                 const float* __restrict__ bias, float* __restrict__ out) {
  __shared__ u16 As[BM * LDT];
  __shared__ u16 Bs[BN * LDT];
  const int tid = threadIdx.x;
  const int m0 = blockIdx.x * BM;
  const int n0 = blockIdx.y * BN;
  const int lane = tid & 63;
  const int wave = tid >> 6;
  const int wm = (wave & 1) * 64;
  const int wn = (wave >> 1) * 64;
  const int fr = lane & 15;        // A row / B col within 16-tile
  const int fq = lane >> 4;        // quad -> k-subrange / C row group

  f32x4 acc[4][4];
#pragma unroll
  for (int i = 0; i < 4; ++i)
#pragma unroll
    for (int j = 0; j < 4; ++j) acc[i][j] = (f32x4){0.f, 0.f, 0.f, 0.f};

  // staging: 512 16B-chunks per tile (128 rows x 4 chunks); thread does c, c+256
  const int r0 = tid >> 2, kc0 = (tid & 3) * 8;
  const int r1 = (tid + 256) >> 2, kc1 = ((tid + 256) & 3) * 8;

  for (int k0 = 0; k0 < Dv; k0 += BK) {
    __syncthreads();
    *(bf16x8*)(As + r0 * LDT + kc0) = *(const bf16x8*)(A + (size_t)(m0 + r0) * Dv + k0 + kc0);
    *(bf16x8*)(As + r1 * LDT + kc1) = *(const bf16x8*)(A + (size_t)(m0 + r1) * Dv + k0 + kc1);
    *(bf16x8*)(Bs + r0 * LDT + kc0) = *(const bf16x8*)(Bw + (size_t)(n0 + r0) * Dv + k0 + kc0);
    *(bf16x8*)(Bs + r1 * LDT + kc1) = *(const bf16x8*)(Bw + (size_t)(n0 + r1) * Dv + k0 + kc1);
    __syncthreads();

    bf16x8 af[4], bfr[4];
#pragma unroll
    for (int mi = 0; mi < 4; ++mi)
      af[mi] = *(const bf16x8*)(As + (wm + mi * 16 + fr) * LDT + fq * 8);
#pragma unroll
    for (int ni = 0; ni < 4; ++ni)
      bfr[ni] = *(const bf16x8*)(Bs + (wn + ni * 16 + fr) * LDT + fq * 8);
#pragma unroll
    for (int mi = 0; mi < 4; ++mi)
#pragma unroll
      for (int ni = 0; ni < 4; ++ni)
        acc[mi][ni] = __builtin_amdgcn_mfma_f32_16x16x32_bf16(af[mi], bfr[ni], acc[mi][ni], 0, 0, 0);
  }

#pragma unroll
  for (int mi = 0; mi < 4; ++mi) {
#pragma unroll
    for (int ni = 0; ni < 4; ++ni) {
      const int col = n0 + wn + ni * 16 + fr;
      const float bv = bias[col];
#pragma unroll
      for (int r = 0; r < 4; ++r) {
        const int row = m0 + wm + mi * 16 + fq * 4 + r;
        out[(size_t)row * OUTv + col] = acc[mi][ni][r] + bv;
      }
    }
  }
}

// ---------------------------------------------------------------------------
// Workspace layout (bytes):
//   [0,            16777216)  pooled bf16 [M, D]
//   [16777216,     17301504)  Wb bf16 [OUT, D]
//   [17301504,     17367040)  counts int [M]
//   [17367040,     17383424)  avg_sum float [B, D]
//   [17383424,     17383456)  n_fill int [B]
// ---------------------------------------------------------------------------
extern "C" void kernel_launch(void* const* d_in, const int* in_sizes, int n_in,
                              void* d_out, int out_size, void* d_ws, size_t ws_size,
                              hipStream_t stream) {
  (void)in_sizes; (void)n_in; (void)out_size; (void)ws_size;
  const float* rep     = (const float*)d_in[0];
  const int*   res_ids = (const int*)d_in[1];
  const int*   aa_len  = (const int*)d_in[2];
  const int*   seq_len = (const int*)d_in[3];
  const float* W       = (const float*)d_in[4];
  const float* bias    = (const float*)d_in[5];
  float* out = (float*)d_out;

  char* ws = (char*)d_ws;
  u16*   pooled  = (u16*)ws;
  u16*   Wb      = (u16*)(ws + 16777216);
  int*   counts  = (int*)(ws + 17301504);
  float* avg_sum = (float*)(ws + 17367040);
  int*   n_fill  = (int*)(ws + 17383424);

  hipMemsetAsync(avg_sum, 0, Bv * Dv * sizeof(float) + Bv * sizeof(int), stream);

  wconv_kernel<<<(OUTv * Dv) / (256 * 4), 256, 0, stream>>>(W, Wb);
  pool_kernel<<<Mv, 128, 0, stream>>>(rep, res_ids, aa_len, pooled, counts);
  avg_kernel<<<dim3(Bv, 16), 128, 0, stream>>>(pooled, counts, seq_len, avg_sum, n_fill);
  fixup_kernel<<<Mv, 64, 0, stream>>>(pooled, counts, seq_len, avg_sum, n_fill);
  gemm_kernel<<<dim3(Mv / BM, OUTv / BN), 256, 0, stream>>>(pooled, Wb, bias, out);
}